// Round 12
// baseline (93.776 us; speedup 1.0000x reference)
//
#include <hip/hip_runtime.h>
#include <stdint.h>

typedef _Float16 f16x8 __attribute__((ext_vector_type(8)));
typedef _Float16 f16x4 __attribute__((ext_vector_type(4)));
typedef __fp16 half2_t __attribute__((ext_vector_type(2)));
typedef float f32x4 __attribute__((ext_vector_type(4)));

#define LOG2E 1.44269504088896340736f
#define NEGINF (-1e16f)

constexpr int kN = 4096;   // nodes
constexpr int kD = 64;     // feature dim
constexpr int kB = 8;      // batch

// ---------------------------------------------------------------------------
// Kernel 1: h[row][d] = sum_c x[row][c] * W[d][c]  (f32 math, f16 store)
//           also writes hT[b][d][n] via LDS transpose (coalesced stores)
// ---------------------------------------------------------------------------
__global__ __launch_bounds__(256) void hproj_kernel(const float* __restrict__ x,
                                                    const float* __restrict__ W,
                                                    _Float16* __restrict__ hout,
                                                    _Float16* __restrict__ hTout)
{
    __shared__ float Wt[64][64];   // Wt[c][d] = W[d][c]
    __shared__ float xs[64][65];
    __shared__ _Float16 ht[64][68];  // h tile for transpose, padded

    const int tid = threadIdx.x;
    const int r   = tid >> 2;          // 0..63
    const int c0  = (tid & 3) * 16;    // 0,16,32,48

    #pragma unroll
    for (int j = 0; j < 16; j += 4) {
        const float4 v = *(const float4*)(W + r * 64 + c0 + j);
        Wt[c0 + j + 0][r] = v.x;
        Wt[c0 + j + 1][r] = v.y;
        Wt[c0 + j + 2][r] = v.z;
        Wt[c0 + j + 3][r] = v.w;
    }
    const long rowbase = (long)blockIdx.x * 64;
    #pragma unroll
    for (int j = 0; j < 16; j += 4) {
        const float4 v = *(const float4*)(x + (rowbase + r) * 64 + c0 + j);
        xs[r][c0 + j + 0] = v.x;
        xs[r][c0 + j + 1] = v.y;
        xs[r][c0 + j + 2] = v.z;
        xs[r][c0 + j + 3] = v.w;
    }
    __syncthreads();

    const int d0 = (tid & 3) * 16;
    f32x4 acc[4] = {{0.f,0.f,0.f,0.f},{0.f,0.f,0.f,0.f},{0.f,0.f,0.f,0.f},{0.f,0.f,0.f,0.f}};
    #pragma unroll 4
    for (int c = 0; c < 64; ++c) {
        const float xv = xs[r][c];
        const f32x4* wrow = (const f32x4*)&Wt[c][d0];
        #pragma unroll
        for (int k = 0; k < 4; ++k) acc[k] += wrow[k] * xv;
    }
    f16x8 o0, o1;
    #pragma unroll
    for (int j = 0; j < 8; ++j) {
        o0[j] = (_Float16)acc[j >> 2][j & 3];
        o1[j] = (_Float16)acc[2 + (j >> 2)][j & 3];
    }
    *(f16x8*)(hout + (rowbase + r) * 64 + d0)     = o0;
    *(f16x8*)(hout + (rowbase + r) * 64 + d0 + 8) = o1;

    // LDS transpose for hT
    #pragma unroll
    for (int j = 0; j < 8; ++j) {
        ht[r][d0 + j]     = o0[j];
        ht[r][d0 + 8 + j] = o1[j];
    }
    __syncthreads();

    const int bb = blockIdx.x >> 6;                 // 64 blocks per batch
    const int n0 = (int)(rowbase & (kN - 1));
    const int dr = tid >> 2;                        // output d row
    const int c4 = (tid & 3) * 16;                  // n-column group
    f16x8 t0, t1;
    #pragma unroll
    for (int j = 0; j < 8; ++j) {
        t0[j] = ht[c4 + j][dr];
        t1[j] = ht[c4 + 8 + j][dr];
    }
    _Float16* dst = hTout + (long)bb * kD * kN + (long)dr * kN + n0 + c4;
    *(f16x8*)(dst)     = t0;
    *(f16x8*)(dst + 8) = t1;
}

// ---------------------------------------------------------------------------
// Kernel 2: bit-pack graph (int32 0/1, [4096][4096]) -> uint32 [4096][128]
// ---------------------------------------------------------------------------
__global__ __launch_bounds__(256) void bitpack_kernel(const int* __restrict__ g,
                                                      uint32_t* __restrict__ mw)
{
    const long w = (long)blockIdx.x * 256 + threadIdx.x;  // word index
    const int4* p = (const int4*)(g + w * 32);
    uint32_t bits = 0;
    #pragma unroll
    for (int j = 0; j < 8; ++j) {
        const int4 v = p[j];
        bits |= (uint32_t)(v.x != 0) << (j * 4 + 0);
        bits |= (uint32_t)(v.y != 0) << (j * 4 + 1);
        bits |= (uint32_t)(v.z != 0) << (j * 4 + 2);
        bits |= (uint32_t)(v.w != 0) << (j * 4 + 3);
    }
    mw[w] = bits;
}

// ---------------------------------------------------------------------------
// Kernel 2b: transpose bitmask into per-slot 64-bit LANE masks.
// wm[(q16*64 + kv64)*16 + s]: bit for lane l=(lg*16+ll) =
//   graph[q16*16+ll][kv64*64 + 32*(t>>1)+8*lg+4*(t&1)+rr],  s = t*4+rr
// ---------------------------------------------------------------------------
__global__ __launch_bounds__(256) void masktr_kernel(const uint32_t* __restrict__ mw,
                                                     uint64_t* __restrict__ wmout)
{
    const int tid  = threadIdx.x;
    const int wv   = tid >> 6;
    const int lane = tid & 63;
    const int ll   = lane & 15;
    const int lg   = lane >> 4;
    const int pair = blockIdx.x * 4 + wv;          // 0..16383
    const int q16  = pair >> 6;
    const int kv64 = pair & 63;

    const uint2 u = *(const uint2*)(mw + (long)(q16 * 16 + ll) * 128 + kv64 * 2);

    uint64_t Wb[16];
    #pragma unroll
    for (int s = 0; s < 16; ++s) {
        const int t = s >> 2, rr = s & 3;
        const uint32_t word = (t >= 2) ? u.y : u.x;
        const int pos = 8 * lg + 4 * (t & 1) + rr;
        Wb[s] = __ballot(((word >> pos) & 1u) != 0);
    }

    const int s = lane;
    uint64_t a0 = (s & 1) ? Wb[1]  : Wb[0];
    uint64_t a1 = (s & 1) ? Wb[3]  : Wb[2];
    uint64_t a2 = (s & 1) ? Wb[5]  : Wb[4];
    uint64_t a3 = (s & 1) ? Wb[7]  : Wb[6];
    uint64_t a4 = (s & 1) ? Wb[9]  : Wb[8];
    uint64_t a5 = (s & 1) ? Wb[11] : Wb[10];
    uint64_t a6 = (s & 1) ? Wb[13] : Wb[12];
    uint64_t a7 = (s & 1) ? Wb[15] : Wb[14];
    uint64_t b0 = (s & 2) ? a1 : a0;
    uint64_t b1 = (s & 2) ? a3 : a2;
    uint64_t b2 = (s & 2) ? a5 : a4;
    uint64_t b3 = (s & 2) ? a7 : a6;
    uint64_t c0 = (s & 4) ? b1 : b0;
    uint64_t c1 = (s & 4) ? b3 : b2;
    uint64_t v  = (s & 8) ? c1 : c0;
    if (lane < 16) wmout[(long)pair * 16 + lane] = v;
}

// ---------------------------------------------------------------------------
// Kernel 3: swapped-operand flash attention over a KV chunk.
// grid (32, 8, KS), 512 thr (8 waves); wave handles 16 q rows (block: 128).
// ROUND-11 PROVEN BODY. Partials stored NORMALIZED (O/l) in f16 — bounded by
// max|v|, no overflow; combine weights by l*e^(m-M) (exact algebra).
// ---------------------------------------------------------------------------
__global__ __launch_bounds__(512) void attn_kernel(const _Float16* __restrict__ h,
                                                   const _Float16* __restrict__ hT,
                                                   const uint64_t* __restrict__ wmask,
                                                   const float* __restrict__ bias,
                                                   float* __restrict__ outp,
                                                   _Float16* __restrict__ pO,
                                                   float* __restrict__ pml,
                                                   int kvlen)
{
    __shared__ alignas(16) char Kl[2][8192];
    __shared__ alignas(16) char Vt[2][8192];

    const int b     = blockIdx.y;
    const int split = blockIdx.z;
    const int q0    = blockIdx.x * 128;
    const int tid   = threadIdx.x;
    const int wave  = tid >> 6;
    const int lane  = tid & 63;
    const int lg    = lane >> 4;   // 0..3
    const int ll    = lane & 15;   // 0..15

    const _Float16* hb  = h  + (long)b * kN * kD;
    const _Float16* hTb = hT + (long)b * kD * kN;
    const int kv_base = split * kvlen;
    const int NT      = kvlen / 64;

    // Q fragment (B-operand: lane holds Q[q=ll][c=8*lg+e]), resident
    const int q = q0 + wave * 16 + ll;
    const f16x8 qf0 = *(const f16x8*)(hb + q * 64 + lg * 8);
    const f16x8 qf1 = *(const f16x8*)(hb + q * 64 + 32 + lg * 8);

    // constant 5th V-row A-fragment: ones iff ll==0
    f16x8 vone;
    {
        const _Float16 o = (ll == 0) ? (_Float16)1.0f : (_Float16)0.0f;
        #pragma unroll
        for (int j = 0; j < 8; ++j) vone[j] = o;
    }

    f32x4 Oacc[4] = {{0.f,0.f,0.f,0.f},{0.f,0.f,0.f,0.f},{0.f,0.f,0.f,0.f},{0.f,0.f,0.f,0.f}};
    f32x4 Oacc4 = {0.f, 0.f, 0.f, 0.f};
    float m_run = NEGINF;
    float mm = NEGINF * LOG2E;
    float negv = NEGINF;

    // staging mapping: 512 threads, thread stages 8 K elems + 8 V elems
    const int sr  = tid >> 3;          // 0..63
    const int sc8 = (tid & 7) * 8;     // 0..56
    const int srp = (sr & 0x23) | ((sr & 0x18) >> 1) | ((sr & 0x4) << 2);

    const int kw = srp * 128 + ((sc8 * 2) ^ ((srp & 7) << 4));
    const int vw = sr  * 128 + ((sc8 * 2) ^ ((sr  & 7) << 4));
    const int rb0 = ll * 128 + (((lg * 16))      ^ ((ll & 7) << 4));
    const int rb1 = ll * 128 + (((64 + lg * 16)) ^ ((ll & 7) << 4));

    char* const KB = (char*)Kl;
    char* const VB = (char*)Vt;

    const _Float16* gK = hb  + (long)(kv_base + sr) * 64 + sc8;
    const _Float16* gV = hTb + (long)sr * kN + kv_base + sc8;

    // wave-uniform lane-mask pointer
    const int wuni = __builtin_amdgcn_readfirstlane(wave);
    const uint64_t* __restrict__ wmp =
        wmask + ((long)(blockIdx.x * 8 + wuni) * 64 + (kv_base >> 6)) * 16;

    // ---- stage tile 0 + mask tile 0 ----
    uint64_t wmA[16], wmB[16];
    {
        const f16x8 a0 = *(const f16x8*)(gK);
        const f16x8 b0 = *(const f16x8*)(gV);
        *(f16x8*)(KB + kw) = a0;
        *(f16x8*)(VB + vw) = b0;
        gK += 64 * 64;  gV += 64;
        #pragma unroll
        for (int s = 0; s < 16; ++s) wmA[s] = wmp[s];
    }

#define TILE_BODY(WMC, WMN, IT, CB, NB)                                          \
    do {                                                                         \
        const int it_ = (IT);                                                    \
        /* issue next tile's global loads (vmcnt) BEFORE the barrier */          \
        f16x8 nk0{}, nv0{};                                                      \
        if (it_ + 1 < NT) {                                                      \
            nk0 = *(const f16x8*)(gK);                                           \
            nv0 = *(const f16x8*)(gV);                                           \
            gK += 64 * 64;  gV += 64;                                            \
        }                                                                        \
        /* raw barrier: drain LDS (ds) only; vmcnt stays in flight */            \
        asm volatile("s_waitcnt lgkmcnt(0)" ::: "memory");                       \
        __builtin_amdgcn_s_barrier();                                            \
        __builtin_amdgcn_sched_barrier(0);                                       \
        /* next tile's mask words (lgkm) issued after the drain */               \
        if (it_ + 1 < NT) {                                                      \
            _Pragma("unroll")                                                    \
            for (int s5 = 0; s5 < 16; ++s5) WMN[s5] = wmp[(long)(it_+1)*16 + s5];\
        }                                                                        \
        f32x4 S[4];                                                              \
        _Pragma("unroll")                                                        \
        for (int t = 0; t < 4; ++t) {                                            \
            const f16x8 k0 = *(const f16x8*)(KB + (CB) + rb0 + t * 2048);        \
            const f16x8 k1 = *(const f16x8*)(KB + (CB) + rb1 + t * 2048);        \
            f32x4 s = {0.f, 0.f, 0.f, 0.f};                                      \
            s = __builtin_amdgcn_mfma_f32_16x16x32_f16(k0, qf0, s, 0, 0, 0);     \
            s = __builtin_amdgcn_mfma_f32_16x16x32_f16(k1, qf1, s, 0, 0, 0);     \
            S[t] = s;                                                            \
        }                                                                        \
        /* write prefetched tile (first use of nk0/nv0 -> vmcnt wait here) */    \
        if (it_ + 1 < NT) {                                                      \
            *(f16x8*)(KB + (NB) + kw) = nk0;                                     \
            *(f16x8*)(VB + (NB) + vw) = nv0;                                     \
        }                                                                        \
        _Pragma("unroll")                                                        \
        for (int t = 0; t < 4; ++t) {                                            \
            _Pragma("unroll")                                                    \
            for (int rr = 0; rr < 4; ++rr) {                                     \
                float sv = S[t][rr];                                             \
                asm("v_cndmask_b32 %0, %1, %2, %3"                               \
                    : "=v"(sv) : "v"(negv), "v"(sv), "s"(WMC[t * 4 + rr]));      \
                S[t][rr] = sv;                                                   \
            }                                                                    \
        }                                                                        \
        /* chain-form max (enables v_max3 fusion, T17) */                        \
        float mx0 = fmaxf(fmaxf(fmaxf(S[0][0], S[0][1]), S[0][2]), S[0][3]);     \
        float mx1 = fmaxf(fmaxf(fmaxf(S[1][0], S[1][1]), S[1][2]), S[1][3]);     \
        float mx2 = fmaxf(fmaxf(fmaxf(S[2][0], S[2][1]), S[2][2]), S[2][3]);     \
        float mx3 = fmaxf(fmaxf(fmaxf(S[3][0], S[3][1]), S[3][2]), S[3][3]);     \
        float mloc = fmaxf(fmaxf(fmaxf(mx0, mx1), mx2), mx3);                    \
        mloc = fmaxf(mloc, __shfl_xor(mloc, 16));                                \
        mloc = fmaxf(mloc, __shfl_xor(mloc, 32));                                \
        if (__any(mloc > m_run + 8.f)) {                                         \
            const float mnew = fmaxf(m_run, mloc);                               \
            const float scl  = __builtin_amdgcn_exp2f((m_run - mnew) * LOG2E);   \
            m_run = mnew;                                                        \
            mm    = mnew * LOG2E;                                                \
            _Pragma("unroll")                                                    \
            for (int dt = 0; dt < 4; ++dt) Oacc[dt] *= scl;                      \
            Oacc4 *= scl;                                                        \
        }                                                                        \
        _Pragma("unroll")                                                        \
        for (int t = 0; t < 4; ++t) {                                            \
            _Pragma("unroll")                                                    \
            for (int rr = 0; rr < 4; ++rr)                                       \
                S[t][rr] = __builtin_amdgcn_exp2f(fmaf(S[t][rr], LOG2E, -mm));   \
        }                                                                        \
        union PF { half2_t hh[4]; f16x8 v; };                                    \
        PF pf1, pf2;                                                             \
        pf1.hh[0] = __builtin_amdgcn_cvt_pkrtz(S[0][0], S[0][1]);                \
        pf1.hh[1] = __builtin_amdgcn_cvt_pkrtz(S[0][2], S[0][3]);                \
        pf1.hh[2] = __builtin_amdgcn_cvt_pkrtz(S[1][0], S[1][1]);                \
        pf1.hh[3] = __builtin_amdgcn_cvt_pkrtz(S[1][2], S[1][3]);                \
        pf2.hh[0] = __builtin_amdgcn_cvt_pkrtz(S[2][0], S[2][1]);                \
        pf2.hh[1] = __builtin_amdgcn_cvt_pkrtz(S[2][2], S[2][3]);                \
        pf2.hh[2] = __builtin_amdgcn_cvt_pkrtz(S[3][0], S[3][1]);                \
        pf2.hh[3] = __builtin_amdgcn_cvt_pkrtz(S[3][2], S[3][3]);                \
        _Pragma("unroll")                                                        \
        for (int dt = 0; dt < 4; ++dt) {                                         \
            const f16x8 v0 = *(const f16x8*)(VB + (CB) + rb0 + dt * 2048);       \
            const f16x8 v1 = *(const f16x8*)(VB + (CB) + rb1 + dt * 2048);       \
            Oacc[dt] = __builtin_amdgcn_mfma_f32_16x16x32_f16(v0, pf1.v, Oacc[dt], 0, 0, 0); \
            Oacc[dt] = __builtin_amdgcn_mfma_f32_16x16x32_f16(v1, pf2.v, Oacc[dt], 0, 0, 0); \
        }                                                                        \
        Oacc4 = __builtin_amdgcn_mfma_f32_16x16x32_f16(vone, pf1.v, Oacc4, 0, 0, 0); \
        Oacc4 = __builtin_amdgcn_mfma_f32_16x16x32_f16(vone, pf2.v, Oacc4, 0, 0, 0); \
    } while (0)

    for (int ith = 0; ith < NT; ith += 2) {
        TILE_BODY(wmA, wmB, ith,     0,    8192);
        TILE_BODY(wmB, wmA, ith + 1, 8192, 0);
    }
#undef TILE_BODY

    // ---- l broadcast: lane (lg=0, ll) holds l_q in Oacc4[0] ----
    const float lsum = __shfl(Oacc4[0], ll, 64);
    const float inv  = (lsum > 0.f) ? (1.0f / lsum) : 0.f;

    // ---- epilogue: lane owns q = ll, d = 16*dt + 4*lg + rr ----
    if (outp != nullptr) {
        #pragma unroll
        for (int dt = 0; dt < 4; ++dt) {
            const int dbase = dt * 16 + lg * 4;
            const f32x4 bv = *(const f32x4*)(bias + dbase);
            f32x4 o;
            #pragma unroll
            for (int rr = 0; rr < 4; ++rr) o[rr] = Oacc[dt][rr] * inv + bv[rr];
            *(f32x4*)(outp + ((long)b * kN + q) * 64 + dbase) = o;
        }
    } else {
        // normalized f16 partials (bounded by max|v|): Ō = O/l
        const long srow = (long)split * kB * kN + (long)b * kN + q;
        #pragma unroll
        for (int dt = 0; dt < 4; ++dt) {
            const int dbase = dt * 16 + lg * 4;
            f16x4 po;
            #pragma unroll
            for (int rr = 0; rr < 4; ++rr) po[rr] = (_Float16)(Oacc[dt][rr] * inv);
            *(f16x4*)(pO + srow * 64 + dbase) = po;
        }
        if (lane < 16) {
            pml[srow * 2 + 0] = m_run;
            pml[srow * 2 + 1] = lsum;
        }
    }
}

// ---------------------------------------------------------------------------
// Kernel 4: combine split-KV partials (normalized f16; weight = l*e^(m-M)).
// ---------------------------------------------------------------------------
__global__ __launch_bounds__(256) void combine_kernel(const _Float16* __restrict__ pO,
                                                      const float* __restrict__ pml,
                                                      const float* __restrict__ bias,
                                                      float* __restrict__ outp,
                                                      int ks)
{
    const long idx = (long)blockIdx.x * 256 + threadIdx.x;  // B*N*16 groups
    const long row = idx >> 4;
    const int  d4  = (int)(idx & 15) * 4;

    float M = NEGINF;
    for (int s = 0; s < ks; ++s)
        M = fmaxf(M, pml[((long)s * kB * kN + row) * 2]);

    float L = 0.f;
    f32x4 acc = {0.f, 0.f, 0.f, 0.f};
    for (int s = 0; s < ks; ++s) {
        const long srow = (long)s * kB * kN + row;
        const float m = pml[srow * 2 + 0];
        const float l = pml[srow * 2 + 1];
        const float w = l * __builtin_amdgcn_exp2f((m - M) * LOG2E);
        L += w;
        const f16x4 o = *(const f16x4*)(pO + srow * 64 + d4);
        #pragma unroll
        for (int j = 0; j < 4; ++j) acc[j] += (float)o[j] * w;
    }
    const float invL = (L > 0.f) ? (1.0f / L) : 0.f;
    const f32x4 bv = *(const f32x4*)(bias + d4);
    *(f32x4*)(outp + row * 64 + d4) = acc * invL + bv;
}

// ---------------------------------------------------------------------------
extern "C" void kernel_launch(void* const* d_in, const int* in_sizes, int n_in,
                              void* d_out, int out_size, void* d_ws, size_t ws_size,
                              hipStream_t stream) {
    const float*  x     = (const float*)d_in[0];   // [8,4096,64]
    const int*    graph = (const int*)d_in[1];     // [4096,4096]
    const float*  W     = (const float*)d_in[2];   // [64,64]
    const float*  bias  = (const float*)d_in[3];   // [64]
    float*        outp  = (float*)d_out;

    char* ws = (char*)d_ws;
    _Float16* hptr  = (_Float16*)ws;                          // 4 MiB @ 0
    uint32_t* mwptr = (uint32_t*)(ws + (4u << 20));           // 2 MiB @ 4M
    _Float16* hTptr = (_Float16*)(ws + (6u << 20));           // 4 MiB @ 6M
    uint64_t* wmptr = (uint64_t*)(ws + (10u << 20));          // 2 MiB @ 10M

    // pO: ks * 4 MiB (f16 normalized), pml: ks * 256 KiB
    int ks = 1;
    if      (ws_size >= ((size_t)47 << 20)) ks = 8;
    else if (ws_size >= ((size_t)30 << 20)) ks = 4;
    else if (ws_size >= ((size_t)21 << 20)) ks = 2;

    _Float16* pO  = (_Float16*)(ws + (12u << 20));
    float*    pml = (float*)(ws + (12u << 20) + (size_t)ks * (4u << 20));

    hproj_kernel<<<dim3(kB * kN / 64), dim3(256), 0, stream>>>(x, W, hptr, hTptr);
    bitpack_kernel<<<dim3(kN * (kN / 32) / 256), dim3(256), 0, stream>>>(graph, mwptr);
    masktr_kernel<<<dim3(256 * 64 / 4), dim3(256), 0, stream>>>(mwptr, wmptr);

    if (ks == 1) {
        attn_kernel<<<dim3(kN / 128, kB, 1), dim3(512), 0, stream>>>(
            hptr, hTptr, wmptr, bias, outp, nullptr, nullptr, kN);
    } else {
        attn_kernel<<<dim3(kN / 128, kB, ks), dim3(512), 0, stream>>>(
            hptr, hTptr, wmptr, bias, nullptr, pO, pml, kN / ks);
        combine_kernel<<<dim3(kB * kN * 16 / 256), dim3(256), 0, stream>>>(
            pO, pml, bias, outp, ks);
    }
}

// Round 13
// 87.242 us; speedup vs baseline: 1.0749x; 1.0749x over previous
//
#include <hip/hip_runtime.h>
#include <stdint.h>

typedef _Float16 f16x8 __attribute__((ext_vector_type(8)));
typedef _Float16 f16x4 __attribute__((ext_vector_type(4)));
typedef __fp16 half2_t __attribute__((ext_vector_type(2)));
typedef float f32x4 __attribute__((ext_vector_type(4)));

#define LOG2E 1.44269504088896340736f
#define NEGINF (-1e16f)

constexpr int kN = 4096;   // nodes
constexpr int kD = 64;     // feature dim
constexpr int kB = 8;      // batch

// ---------------------------------------------------------------------------
// Kernel 1: h[row][d] = sum_c x[row][c] * W[d][c]  (f32 math, f16 store)
//           also writes hT[b][d][n] via LDS transpose (coalesced stores)
// ---------------------------------------------------------------------------
__global__ __launch_bounds__(256) void hproj_kernel(const float* __restrict__ x,
                                                    const float* __restrict__ W,
                                                    _Float16* __restrict__ hout,
                                                    _Float16* __restrict__ hTout)
{
    __shared__ float Wt[64][64];   // Wt[c][d] = W[d][c]
    __shared__ float xs[64][65];
    __shared__ _Float16 ht[64][68];  // h tile for transpose, padded

    const int tid = threadIdx.x;
    const int r   = tid >> 2;          // 0..63
    const int c0  = (tid & 3) * 16;    // 0,16,32,48

    #pragma unroll
    for (int j = 0; j < 16; j += 4) {
        const float4 v = *(const float4*)(W + r * 64 + c0 + j);
        Wt[c0 + j + 0][r] = v.x;
        Wt[c0 + j + 1][r] = v.y;
        Wt[c0 + j + 2][r] = v.z;
        Wt[c0 + j + 3][r] = v.w;
    }
    const long rowbase = (long)blockIdx.x * 64;
    #pragma unroll
    for (int j = 0; j < 16; j += 4) {
        const float4 v = *(const float4*)(x + (rowbase + r) * 64 + c0 + j);
        xs[r][c0 + j + 0] = v.x;
        xs[r][c0 + j + 1] = v.y;
        xs[r][c0 + j + 2] = v.z;
        xs[r][c0 + j + 3] = v.w;
    }
    __syncthreads();

    const int d0 = (tid & 3) * 16;
    f32x4 acc[4] = {{0.f,0.f,0.f,0.f},{0.f,0.f,0.f,0.f},{0.f,0.f,0.f,0.f},{0.f,0.f,0.f,0.f}};
    #pragma unroll 4
    for (int c = 0; c < 64; ++c) {
        const float xv = xs[r][c];
        const f32x4* wrow = (const f32x4*)&Wt[c][d0];
        #pragma unroll
        for (int k = 0; k < 4; ++k) acc[k] += wrow[k] * xv;
    }
    f16x8 o0, o1;
    #pragma unroll
    for (int j = 0; j < 8; ++j) {
        o0[j] = (_Float16)acc[j >> 2][j & 3];
        o1[j] = (_Float16)acc[2 + (j >> 2)][j & 3];
    }
    *(f16x8*)(hout + (rowbase + r) * 64 + d0)     = o0;
    *(f16x8*)(hout + (rowbase + r) * 64 + d0 + 8) = o1;

    // LDS transpose for hT
    #pragma unroll
    for (int j = 0; j < 8; ++j) {
        ht[r][d0 + j]     = o0[j];
        ht[r][d0 + 8 + j] = o1[j];
    }
    __syncthreads();

    const int bb = blockIdx.x >> 6;                 // 64 blocks per batch
    const int n0 = (int)(rowbase & (kN - 1));
    const int dr = tid >> 2;                        // output d row
    const int c4 = (tid & 3) * 16;                  // n-column group
    f16x8 t0, t1;
    #pragma unroll
    for (int j = 0; j < 8; ++j) {
        t0[j] = ht[c4 + j][dr];
        t1[j] = ht[c4 + 8 + j][dr];
    }
    _Float16* dst = hTout + (long)bb * kD * kN + (long)dr * kN + n0 + c4;
    *(f16x8*)(dst)     = t0;
    *(f16x8*)(dst + 8) = t1;
}

// ---------------------------------------------------------------------------
// Kernel 2: bit-pack graph (int32 0/1, [4096][4096]) -> uint32 [4096][128]
// ---------------------------------------------------------------------------
__global__ __launch_bounds__(256) void bitpack_kernel(const int* __restrict__ g,
                                                      uint32_t* __restrict__ mw)
{
    const long w = (long)blockIdx.x * 256 + threadIdx.x;  // word index
    const int4* p = (const int4*)(g + w * 32);
    uint32_t bits = 0;
    #pragma unroll
    for (int j = 0; j < 8; ++j) {
        const int4 v = p[j];
        bits |= (uint32_t)(v.x != 0) << (j * 4 + 0);
        bits |= (uint32_t)(v.y != 0) << (j * 4 + 1);
        bits |= (uint32_t)(v.z != 0) << (j * 4 + 2);
        bits |= (uint32_t)(v.w != 0) << (j * 4 + 3);
    }
    mw[w] = bits;
}

// ---------------------------------------------------------------------------
// Kernel 2b: transpose bitmask into per-slot 64-bit LANE masks.
// wm[(q16*64 + kv64)*16 + s]: bit for lane l=(lg*16+ll) =
//   graph[q16*16+ll][kv64*64 + 32*(t>>1)+8*lg+4*(t&1)+rr],  s = t*4+rr
// ---------------------------------------------------------------------------
__global__ __launch_bounds__(256) void masktr_kernel(const uint32_t* __restrict__ mw,
                                                     uint64_t* __restrict__ wmout)
{
    const int tid  = threadIdx.x;
    const int wv   = tid >> 6;
    const int lane = tid & 63;
    const int ll   = lane & 15;
    const int lg   = lane >> 4;
    const int pair = blockIdx.x * 4 + wv;          // 0..16383
    const int q16  = pair >> 6;
    const int kv64 = pair & 63;

    const uint2 u = *(const uint2*)(mw + (long)(q16 * 16 + ll) * 128 + kv64 * 2);

    uint64_t Wb[16];
    #pragma unroll
    for (int s = 0; s < 16; ++s) {
        const int t = s >> 2, rr = s & 3;
        const uint32_t word = (t >= 2) ? u.y : u.x;
        const int pos = 8 * lg + 4 * (t & 1) + rr;
        Wb[s] = __ballot(((word >> pos) & 1u) != 0);
    }

    const int s = lane;
    uint64_t a0 = (s & 1) ? Wb[1]  : Wb[0];
    uint64_t a1 = (s & 1) ? Wb[3]  : Wb[2];
    uint64_t a2 = (s & 1) ? Wb[5]  : Wb[4];
    uint64_t a3 = (s & 1) ? Wb[7]  : Wb[6];
    uint64_t a4 = (s & 1) ? Wb[9]  : Wb[8];
    uint64_t a5 = (s & 1) ? Wb[11] : Wb[10];
    uint64_t a6 = (s & 1) ? Wb[13] : Wb[12];
    uint64_t a7 = (s & 1) ? Wb[15] : Wb[14];
    uint64_t b0 = (s & 2) ? a1 : a0;
    uint64_t b1 = (s & 2) ? a3 : a2;
    uint64_t b2 = (s & 2) ? a5 : a4;
    uint64_t b3 = (s & 2) ? a7 : a6;
    uint64_t c0 = (s & 4) ? b1 : b0;
    uint64_t c1 = (s & 4) ? b3 : b2;
    uint64_t v  = (s & 8) ? c1 : c0;
    if (lane < 16) wmout[(long)pair * 16 + lane] = v;
}

// ---------------------------------------------------------------------------
// Kernel 3: swapped-operand flash attention, PAIR-TILE (128 kv per pass).
// grid (32, 8, KS), 512 thr (8 waves); wave handles 16 q rows (block: 128).
// Two 64-kv sub-tiles share one barrier / one softmax pass / one rescale.
// LDS 64 KB: K[4][8192] + V[4][8192] (pair = 2 consecutive sub-buffers).
// Masks: 32 uint64 s_loads per pair, loaded post-barrier (QK covers latency).
// Partials normalized f16 (round-12-proven).
// ---------------------------------------------------------------------------
__global__ __launch_bounds__(512) void attn_kernel(const _Float16* __restrict__ h,
                                                   const _Float16* __restrict__ hT,
                                                   const uint64_t* __restrict__ wmask,
                                                   const float* __restrict__ bias,
                                                   float* __restrict__ outp,
                                                   _Float16* __restrict__ pO,
                                                   float* __restrict__ pml,
                                                   int kvlen)
{
    __shared__ alignas(16) char Kl[4][8192];
    __shared__ alignas(16) char Vt[4][8192];

    const int b     = blockIdx.y;
    const int split = blockIdx.z;
    const int q0    = blockIdx.x * 128;
    const int tid   = threadIdx.x;
    const int wave  = tid >> 6;
    const int lane  = tid & 63;
    const int lg    = lane >> 4;   // 0..3
    const int ll    = lane & 15;   // 0..15

    const _Float16* hb  = h  + (long)b * kN * kD;
    const _Float16* hTb = hT + (long)b * kD * kN;
    const int kv_base = split * kvlen;
    const int NP      = kvlen / 128;   // pair count

    // Q fragment (B-operand: lane holds Q[q=ll][c=8*lg+e]), resident
    const int q = q0 + wave * 16 + ll;
    const f16x8 qf0 = *(const f16x8*)(hb + q * 64 + lg * 8);
    const f16x8 qf1 = *(const f16x8*)(hb + q * 64 + 32 + lg * 8);

    // constant 5th V-row A-fragment: ones iff ll==0
    f16x8 vone;
    {
        const _Float16 o = (ll == 0) ? (_Float16)1.0f : (_Float16)0.0f;
        #pragma unroll
        for (int j = 0; j < 8; ++j) vone[j] = o;
    }

    f32x4 Oacc[4] = {{0.f,0.f,0.f,0.f},{0.f,0.f,0.f,0.f},{0.f,0.f,0.f,0.f},{0.f,0.f,0.f,0.f}};
    f32x4 Oacc4 = {0.f, 0.f, 0.f, 0.f};
    float m_run = NEGINF;
    float mm = NEGINF * LOG2E;
    float negv = NEGINF;

    // staging mapping: 512 threads, thread stages 8 K + 8 V elems per sub-tile
    const int sr  = tid >> 3;          // 0..63
    const int sc8 = (tid & 7) * 8;     // 0..56
    const int srp = (sr & 0x23) | ((sr & 0x18) >> 1) | ((sr & 0x4) << 2);

    const int kw = srp * 128 + ((sc8 * 2) ^ ((srp & 7) << 4));
    const int vw = sr  * 128 + ((sc8 * 2) ^ ((sr  & 7) << 4));
    const int rb0 = ll * 128 + (((lg * 16))      ^ ((ll & 7) << 4));
    const int rb1 = ll * 128 + (((64 + lg * 16)) ^ ((ll & 7) << 4));

    char* const KB = (char*)Kl;
    char* const VB = (char*)Vt;

    const _Float16* gK = hb  + (long)(kv_base + sr) * 64 + sc8;
    const _Float16* gV = hTb + (long)sr * kN + kv_base + sc8;

    // wave-uniform lane-mask pointer
    const int wuni = __builtin_amdgcn_readfirstlane(wave);
    const uint64_t* __restrict__ wmp =
        wmask + ((long)(blockIdx.x * 8 + wuni) * 64 + (kv_base >> 6)) * 16;

    // ---- stage pair 0 into sub-buffers 0,1 ----
    {
        const f16x8 a0 = *(const f16x8*)(gK);
        const f16x8 a1 = *(const f16x8*)(gK + 4096);
        const f16x8 b0 = *(const f16x8*)(gV);
        const f16x8 b1 = *(const f16x8*)(gV + 64);
        *(f16x8*)(KB + kw)        = a0;
        *(f16x8*)(KB + 8192 + kw) = a1;
        *(f16x8*)(VB + vw)        = b0;
        *(f16x8*)(VB + 8192 + vw) = b1;
        gK += 8192;  gV += 128;
    }

#define PAIR_BODY(IP, CB, NB)                                                    \
    do {                                                                         \
        const int ip_ = (IP);                                                    \
        /* issue next pair's global loads (vmcnt) BEFORE the barrier */          \
        f16x8 nk0{}, nk1{}, nv0{}, nv1{};                                        \
        if (ip_ + 1 < NP) {                                                      \
            nk0 = *(const f16x8*)(gK);                                           \
            nk1 = *(const f16x8*)(gK + 4096);                                    \
            nv0 = *(const f16x8*)(gV);                                           \
            nv1 = *(const f16x8*)(gV + 64);                                      \
            gK += 8192;  gV += 128;                                              \
        }                                                                        \
        /* raw barrier: drain LDS only; vmcnt stays in flight */                 \
        asm volatile("s_waitcnt lgkmcnt(0)" ::: "memory");                       \
        __builtin_amdgcn_s_barrier();                                            \
        __builtin_amdgcn_sched_barrier(0);                                       \
        /* current pair's 32 lane-masks (s_load; QK below covers latency) */     \
        uint64_t WM[32];                                                         \
        _Pragma("unroll")                                                        \
        for (int s5 = 0; s5 < 32; ++s5) WM[s5] = wmp[(long)ip_ * 32 + s5];       \
        /* S^T over 8 sub-tiles: half = t2>>2, t = t2&3 */                       \
        f32x4 S[8];                                                              \
        _Pragma("unroll")                                                        \
        for (int t2 = 0; t2 < 8; ++t2) {                                         \
            const int kbase = (CB) + (t2 >> 2) * 8192 + (t2 & 3) * 2048;         \
            const f16x8 k0 = *(const f16x8*)(KB + kbase + rb0);                  \
            const f16x8 k1 = *(const f16x8*)(KB + kbase + rb1);                  \
            f32x4 s = {0.f, 0.f, 0.f, 0.f};                                      \
            s = __builtin_amdgcn_mfma_f32_16x16x32_f16(k0, qf0, s, 0, 0, 0);     \
            s = __builtin_amdgcn_mfma_f32_16x16x32_f16(k1, qf1, s, 0, 0, 0);     \
            S[t2] = s;                                                           \
        }                                                                        \
        /* write prefetched pair to the other buffer pair */                     \
        if (ip_ + 1 < NP) {                                                      \
            *(f16x8*)(KB + (NB) + kw)        = nk0;                              \
            *(f16x8*)(KB + (NB) + 8192 + kw) = nk1;                              \
            *(f16x8*)(VB + (NB) + vw)        = nv0;                              \
            *(f16x8*)(VB + (NB) + 8192 + vw) = nv1;                              \
        }                                                                        \
        /* mask: select to NEGINF (slot = (t2>>2)*16 + (t2&3)*4 + rr) */         \
        _Pragma("unroll")                                                        \
        for (int t2 = 0; t2 < 8; ++t2) {                                         \
            _Pragma("unroll")                                                    \
            for (int rr = 0; rr < 4; ++rr) {                                     \
                float sv = S[t2][rr];                                            \
                asm("v_cndmask_b32 %0, %1, %2, %3"                               \
                    : "=v"(sv)                                                   \
                    : "v"(negv), "v"(sv),                                        \
                      "s"(WM[(t2 >> 2) * 16 + (t2 & 3) * 4 + rr]));              \
                S[t2][rr] = sv;                                                  \
            }                                                                    \
        }                                                                        \
        /* one max pass over 32 values */                                        \
        float mloc = NEGINF;                                                     \
        _Pragma("unroll")                                                        \
        for (int t2 = 0; t2 < 8; ++t2)                                           \
            mloc = fmaxf(mloc,                                                   \
                   fmaxf(fmaxf(S[t2][0], S[t2][1]), fmaxf(S[t2][2], S[t2][3]))); \
        mloc = fmaxf(mloc, __shfl_xor(mloc, 16));                                \
        mloc = fmaxf(mloc, __shfl_xor(mloc, 32));                                \
        if (__any(mloc > m_run + 8.f)) {                                         \
            const float mnew = fmaxf(m_run, mloc);                               \
            const float scl  = __builtin_amdgcn_exp2f((m_run - mnew) * LOG2E);   \
            m_run = mnew;                                                        \
            mm    = mnew * LOG2E;                                                \
            _Pragma("unroll")                                                    \
            for (int dt = 0; dt < 4; ++dt) Oacc[dt] *= scl;                      \
            Oacc4 *= scl;                                                        \
        }                                                                        \
        _Pragma("unroll")                                                        \
        for (int t2 = 0; t2 < 8; ++t2) {                                         \
            _Pragma("unroll")                                                    \
            for (int rr = 0; rr < 4; ++rr)                                       \
                S[t2][rr] = __builtin_amdgcn_exp2f(fmaf(S[t2][rr], LOG2E, -mm)); \
        }                                                                        \
        union PF { half2_t hh[4]; f16x8 v; };                                    \
        PF pf[4];                                                                \
        _Pragma("unroll")                                                        \
        for (int pp = 0; pp < 4; ++pp) {                                         \
            pf[pp].hh[0] = __builtin_amdgcn_cvt_pkrtz(S[pp*2][0],   S[pp*2][1]); \
            pf[pp].hh[1] = __builtin_amdgcn_cvt_pkrtz(S[pp*2][2],   S[pp*2][3]); \
            pf[pp].hh[2] = __builtin_amdgcn_cvt_pkrtz(S[pp*2+1][0], S[pp*2+1][1]);\
            pf[pp].hh[3] = __builtin_amdgcn_cvt_pkrtz(S[pp*2+1][2], S[pp*2+1][3]);\
        }                                                                        \
        /* O^T += V^T P^T over both halves */                                    \
        _Pragma("unroll")                                                        \
        for (int dt = 0; dt < 4; ++dt) {                                         \
            const int vb0 = (CB) + rb0 + dt * 2048;                              \
            const int vb1 = (CB) + rb1 + dt * 2048;                              \
            const f16x8 v0 = *(const f16x8*)(VB + vb0);                          \
            const f16x8 v1 = *(const f16x8*)(VB + vb1);                          \
            const f16x8 v2 = *(const f16x8*)(VB + vb0 + 8192);                   \
            const f16x8 v3 = *(const f16x8*)(VB + vb1 + 8192);                   \
            Oacc[dt] = __builtin_amdgcn_mfma_f32_16x16x32_f16(v0, pf[0].v, Oacc[dt], 0, 0, 0); \
            Oacc[dt] = __builtin_amdgcn_mfma_f32_16x16x32_f16(v1, pf[1].v, Oacc[dt], 0, 0, 0); \
            Oacc[dt] = __builtin_amdgcn_mfma_f32_16x16x32_f16(v2, pf[2].v, Oacc[dt], 0, 0, 0); \
            Oacc[dt] = __builtin_amdgcn_mfma_f32_16x16x32_f16(v3, pf[3].v, Oacc[dt], 0, 0, 0); \
        }                                                                        \
        Oacc4 = __builtin_amdgcn_mfma_f32_16x16x32_f16(vone, pf[0].v, Oacc4, 0, 0, 0); \
        Oacc4 = __builtin_amdgcn_mfma_f32_16x16x32_f16(vone, pf[1].v, Oacc4, 0, 0, 0); \
        Oacc4 = __builtin_amdgcn_mfma_f32_16x16x32_f16(vone, pf[2].v, Oacc4, 0, 0, 0); \
        Oacc4 = __builtin_amdgcn_mfma_f32_16x16x32_f16(vone, pf[3].v, Oacc4, 0, 0, 0); \
    } while (0)

    for (int ipp = 0; ipp < NP; ipp += 2) {
        PAIR_BODY(ipp,     0,     16384);
        PAIR_BODY(ipp + 1, 16384, 0);
    }
#undef PAIR_BODY

    // ---- l broadcast: lane (lg=0, ll) holds l_q in Oacc4[0] ----
    const float lsum = __shfl(Oacc4[0], ll, 64);
    const float inv  = (lsum > 0.f) ? (1.0f / lsum) : 0.f;

    // ---- epilogue: lane owns q = ll, d = 16*dt + 4*lg + rr ----
    if (outp != nullptr) {
        #pragma unroll
        for (int dt = 0; dt < 4; ++dt) {
            const int dbase = dt * 16 + lg * 4;
            const f32x4 bv = *(const f32x4*)(bias + dbase);
            f32x4 o;
            #pragma unroll
            for (int rr = 0; rr < 4; ++rr) o[rr] = Oacc[dt][rr] * inv + bv[rr];
            *(f32x4*)(outp + ((long)b * kN + q) * 64 + dbase) = o;
        }
    } else {
        // normalized f16 partials (bounded by max|v|): Ō = O/l
        const long srow = (long)split * kB * kN + (long)b * kN + q;
        #pragma unroll
        for (int dt = 0; dt < 4; ++dt) {
            const int dbase = dt * 16 + lg * 4;
            f16x4 po;
            #pragma unroll
            for (int rr = 0; rr < 4; ++rr) po[rr] = (_Float16)(Oacc[dt][rr] * inv);
            *(f16x4*)(pO + srow * 64 + dbase) = po;
        }
        if (lane < 16) {
            pml[srow * 2 + 0] = m_run;
            pml[srow * 2 + 1] = lsum;
        }
    }
}

// ---------------------------------------------------------------------------
// Kernel 4: combine split-KV partials (normalized f16; weight = l*e^(m-M)).
// ---------------------------------------------------------------------------
__global__ __launch_bounds__(256) void combine_kernel(const _Float16* __restrict__ pO,
                                                      const float* __restrict__ pml,
                                                      const float* __restrict__ bias,
                                                      float* __restrict__ outp,
                                                      int ks)
{
    const long idx = (long)blockIdx.x * 256 + threadIdx.x;  // B*N*16 groups
    const long row = idx >> 4;
    const int  d4  = (int)(idx & 15) * 4;

    float M = NEGINF;
    for (int s = 0; s < ks; ++s)
        M = fmaxf(M, pml[((long)s * kB * kN + row) * 2]);

    float L = 0.f;
    f32x4 acc = {0.f, 0.f, 0.f, 0.f};
    for (int s = 0; s < ks; ++s) {
        const long srow = (long)s * kB * kN + row;
        const float m = pml[srow * 2 + 0];
        const float l = pml[srow * 2 + 1];
        const float w = l * __builtin_amdgcn_exp2f((m - M) * LOG2E);
        L += w;
        const f16x4 o = *(const f16x4*)(pO + srow * 64 + d4);
        #pragma unroll
        for (int j = 0; j < 4; ++j) acc[j] += (float)o[j] * w;
    }
    const float invL = (L > 0.f) ? (1.0f / L) : 0.f;
    const f32x4 bv = *(const f32x4*)(bias + d4);
    *(f32x4*)(outp + row * 64 + d4) = acc * invL + bv;
}

// ---------------------------------------------------------------------------
extern "C" void kernel_launch(void* const* d_in, const int* in_sizes, int n_in,
                              void* d_out, int out_size, void* d_ws, size_t ws_size,
                              hipStream_t stream) {
    const float*  x     = (const float*)d_in[0];   // [8,4096,64]
    const int*    graph = (const int*)d_in[1];     // [4096,4096]
    const float*  W     = (const float*)d_in[2];   // [64,64]
    const float*  bias  = (const float*)d_in[3];   // [64]
    float*        outp  = (float*)d_out;

    char* ws = (char*)d_ws;
    _Float16* hptr  = (_Float16*)ws;                          // 4 MiB @ 0
    uint32_t* mwptr = (uint32_t*)(ws + (4u << 20));           // 2 MiB @ 4M
    _Float16* hTptr = (_Float16*)(ws + (6u << 20));           // 4 MiB @ 6M
    uint64_t* wmptr = (uint64_t*)(ws + (10u << 20));          // 2 MiB @ 10M

    // pO: ks * 4 MiB (f16 normalized), pml: ks * 256 KiB
    int ks = 1;
    if      (ws_size >= ((size_t)30 << 20)) ks = 4;
    else if (ws_size >= ((size_t)21 << 20)) ks = 2;

    _Float16* pO  = (_Float16*)(ws + (12u << 20));
    float*    pml = (float*)(ws + (12u << 20) + (size_t)ks * (4u << 20));

    hproj_kernel<<<dim3(kB * kN / 64), dim3(256), 0, stream>>>(x, W, hptr, hTptr);
    bitpack_kernel<<<dim3(kN * (kN / 32) / 256), dim3(256), 0, stream>>>(graph, mwptr);
    masktr_kernel<<<dim3(256 * 64 / 4), dim3(256), 0, stream>>>(mwptr, wmptr);

    if (ks == 1) {
        attn_kernel<<<dim3(kN / 128, kB, 1), dim3(512), 0, stream>>>(
            hptr, hTptr, wmptr, bias, outp, nullptr, nullptr, kN);
    } else {
        attn_kernel<<<dim3(kN / 128, kB, ks), dim3(512), 0, stream>>>(
            hptr, hTptr, wmptr, bias, nullptr, pO, pml, kN / ks);
        combine_kernel<<<dim3(kB * kN * 16 / 256), dim3(256), 0, stream>>>(
            pO, pml, bias, outp, ks);
    }
}

// Round 14
// 85.234 us; speedup vs baseline: 1.1002x; 1.0236x over previous
//
#include <hip/hip_runtime.h>
#include <stdint.h>

typedef _Float16 f16x8 __attribute__((ext_vector_type(8)));
typedef _Float16 f16x4 __attribute__((ext_vector_type(4)));
typedef __fp16 half2_t __attribute__((ext_vector_type(2)));
typedef float f32x4 __attribute__((ext_vector_type(4)));

#define LOG2E 1.44269504088896340736f
#define NEGINF (-1e16f)

constexpr int kN = 4096;   // nodes
constexpr int kD = 64;     // feature dim
constexpr int kB = 8;      // batch

// ---------------------------------------------------------------------------
// Kernel 1: h[row][d] = sum_c x[row][c] * W[d][c]  (f32 math, f16 store)
//           also writes hT[b][d][n] via LDS transpose (coalesced stores)
// ---------------------------------------------------------------------------
__global__ __launch_bounds__(256) void hproj_kernel(const float* __restrict__ x,
                                                    const float* __restrict__ W,
                                                    _Float16* __restrict__ hout,
                                                    _Float16* __restrict__ hTout)
{
    __shared__ float Wt[64][64];   // Wt[c][d] = W[d][c]
    __shared__ float xs[64][65];
    __shared__ _Float16 ht[64][68];  // h tile for transpose, padded

    const int tid = threadIdx.x;
    const int r   = tid >> 2;          // 0..63
    const int c0  = (tid & 3) * 16;    // 0,16,32,48

    #pragma unroll
    for (int j = 0; j < 16; j += 4) {
        const float4 v = *(const float4*)(W + r * 64 + c0 + j);
        Wt[c0 + j + 0][r] = v.x;
        Wt[c0 + j + 1][r] = v.y;
        Wt[c0 + j + 2][r] = v.z;
        Wt[c0 + j + 3][r] = v.w;
    }
    const long rowbase = (long)blockIdx.x * 64;
    #pragma unroll
    for (int j = 0; j < 16; j += 4) {
        const float4 v = *(const float4*)(x + (rowbase + r) * 64 + c0 + j);
        xs[r][c0 + j + 0] = v.x;
        xs[r][c0 + j + 1] = v.y;
        xs[r][c0 + j + 2] = v.z;
        xs[r][c0 + j + 3] = v.w;
    }
    __syncthreads();

    const int d0 = (tid & 3) * 16;
    f32x4 acc[4] = {{0.f,0.f,0.f,0.f},{0.f,0.f,0.f,0.f},{0.f,0.f,0.f,0.f},{0.f,0.f,0.f,0.f}};
    #pragma unroll 4
    for (int c = 0; c < 64; ++c) {
        const float xv = xs[r][c];
        const f32x4* wrow = (const f32x4*)&Wt[c][d0];
        #pragma unroll
        for (int k = 0; k < 4; ++k) acc[k] += wrow[k] * xv;
    }
    f16x8 o0, o1;
    #pragma unroll
    for (int j = 0; j < 8; ++j) {
        o0[j] = (_Float16)acc[j >> 2][j & 3];
        o1[j] = (_Float16)acc[2 + (j >> 2)][j & 3];
    }
    *(f16x8*)(hout + (rowbase + r) * 64 + d0)     = o0;
    *(f16x8*)(hout + (rowbase + r) * 64 + d0 + 8) = o1;

    // LDS transpose for hT
    #pragma unroll
    for (int j = 0; j < 8; ++j) {
        ht[r][d0 + j]     = o0[j];
        ht[r][d0 + 8 + j] = o1[j];
    }
    __syncthreads();

    const int bb = blockIdx.x >> 6;                 // 64 blocks per batch
    const int n0 = (int)(rowbase & (kN - 1));
    const int dr = tid >> 2;                        // output d row
    const int c4 = (tid & 3) * 16;                  // n-column group
    f16x8 t0, t1;
    #pragma unroll
    for (int j = 0; j < 8; ++j) {
        t0[j] = ht[c4 + j][dr];
        t1[j] = ht[c4 + 8 + j][dr];
    }
    _Float16* dst = hTout + (long)bb * kD * kN + (long)dr * kN + n0 + c4;
    *(f16x8*)(dst)     = t0;
    *(f16x8*)(dst + 8) = t1;
}

// ---------------------------------------------------------------------------
// Kernel 2: bit-pack graph (int32 0/1, [4096][4096]) -> uint32 [4096][128]
// ---------------------------------------------------------------------------
__global__ __launch_bounds__(256) void bitpack_kernel(const int* __restrict__ g,
                                                      uint32_t* __restrict__ mw)
{
    const long w = (long)blockIdx.x * 256 + threadIdx.x;  // word index
    const int4* p = (const int4*)(g + w * 32);
    uint32_t bits = 0;
    #pragma unroll
    for (int j = 0; j < 8; ++j) {
        const int4 v = p[j];
        bits |= (uint32_t)(v.x != 0) << (j * 4 + 0);
        bits |= (uint32_t)(v.y != 0) << (j * 4 + 1);
        bits |= (uint32_t)(v.z != 0) << (j * 4 + 2);
        bits |= (uint32_t)(v.w != 0) << (j * 4 + 3);
    }
    mw[w] = bits;
}

// ---------------------------------------------------------------------------
// Kernel 2b: transpose bitmask into per-slot 64-bit LANE masks.
// wm[(q16*64 + kv64)*16 + s]: bit for lane l=(lg*16+ll) =
//   graph[q16*16+ll][kv64*64 + 32*(t>>1)+8*lg+4*(t&1)+rr],  s = t*4+rr
// ---------------------------------------------------------------------------
__global__ __launch_bounds__(256) void masktr_kernel(const uint32_t* __restrict__ mw,
                                                     uint64_t* __restrict__ wmout)
{
    const int tid  = threadIdx.x;
    const int wv   = tid >> 6;
    const int lane = tid & 63;
    const int ll   = lane & 15;
    const int lg   = lane >> 4;
    const int pair = blockIdx.x * 4 + wv;          // 0..16383
    const int q16  = pair >> 6;
    const int kv64 = pair & 63;

    const uint2 u = *(const uint2*)(mw + (long)(q16 * 16 + ll) * 128 + kv64 * 2);

    uint64_t Wb[16];
    #pragma unroll
    for (int s = 0; s < 16; ++s) {
        const int t = s >> 2, rr = s & 3;
        const uint32_t word = (t >= 2) ? u.y : u.x;
        const int pos = 8 * lg + 4 * (t & 1) + rr;
        Wb[s] = __ballot(((word >> pos) & 1u) != 0);
    }

    const int s = lane;
    uint64_t a0 = (s & 1) ? Wb[1]  : Wb[0];
    uint64_t a1 = (s & 1) ? Wb[3]  : Wb[2];
    uint64_t a2 = (s & 1) ? Wb[5]  : Wb[4];
    uint64_t a3 = (s & 1) ? Wb[7]  : Wb[6];
    uint64_t a4 = (s & 1) ? Wb[9]  : Wb[8];
    uint64_t a5 = (s & 1) ? Wb[11] : Wb[10];
    uint64_t a6 = (s & 1) ? Wb[13] : Wb[12];
    uint64_t a7 = (s & 1) ? Wb[15] : Wb[14];
    uint64_t b0 = (s & 2) ? a1 : a0;
    uint64_t b1 = (s & 2) ? a3 : a2;
    uint64_t b2 = (s & 2) ? a5 : a4;
    uint64_t b3 = (s & 2) ? a7 : a6;
    uint64_t c0 = (s & 4) ? b1 : b0;
    uint64_t c1 = (s & 4) ? b3 : b2;
    uint64_t v  = (s & 8) ? c1 : c0;
    if (lane < 16) wmout[(long)pair * 16 + lane] = v;
}

// ---------------------------------------------------------------------------
// Kernel 3: swapped-operand flash attention, 32-q WAVES (dual Q fragments).
// grid (16, 8, KS), 512 thr (8 waves); wave handles 32 q rows (block: 256).
// Each K/V ds_read_b128 feeds TWO MFMAs (frag A + frag B): LDS read traffic
// per q*kv is HALVED vs the 16-q wave (we measured r13 as LDS-pipe-bound).
// 64-kv tiles, r11-proven body/addressing; T5 setprio around MFMA clusters.
// Partials normalized f16 (r12-proven).
// ---------------------------------------------------------------------------
__global__ __launch_bounds__(512, 4) void attn_kernel(const _Float16* __restrict__ h,
                                                      const _Float16* __restrict__ hT,
                                                      const uint64_t* __restrict__ wmask,
                                                      const float* __restrict__ bias,
                                                      float* __restrict__ outp,
                                                      _Float16* __restrict__ pO,
                                                      float* __restrict__ pml,
                                                      int kvlen)
{
    __shared__ alignas(16) char Kl[2][8192];
    __shared__ alignas(16) char Vt[2][8192];

    const int b     = blockIdx.y;
    const int split = blockIdx.z;
    const int q0    = blockIdx.x * 256;
    const int tid   = threadIdx.x;
    const int wave  = tid >> 6;
    const int lane  = tid & 63;
    const int lg    = lane >> 4;   // 0..3
    const int ll    = lane & 15;   // 0..15

    const _Float16* hb  = h  + (long)b * kN * kD;
    const _Float16* hTb = hT + (long)b * kD * kN;
    const int kv_base = split * kvlen;
    const int NT      = kvlen / 64;

    // Dual Q fragments: frag A = q rows [wave*32, +16), frag B = [+16, +32)
    const int qA = q0 + wave * 32 + ll;
    const int qB = qA + 16;
    const f16x8 qfA0 = *(const f16x8*)(hb + qA * 64 + lg * 8);
    const f16x8 qfA1 = *(const f16x8*)(hb + qA * 64 + 32 + lg * 8);
    const f16x8 qfB0 = *(const f16x8*)(hb + qB * 64 + lg * 8);
    const f16x8 qfB1 = *(const f16x8*)(hb + qB * 64 + 32 + lg * 8);

    // constant 5th V-row A-fragment: ones iff ll==0
    f16x8 vone;
    {
        const _Float16 o = (ll == 0) ? (_Float16)1.0f : (_Float16)0.0f;
        #pragma unroll
        for (int j = 0; j < 8; ++j) vone[j] = o;
    }

    f32x4 OaccA[4] = {{0.f,0.f,0.f,0.f},{0.f,0.f,0.f,0.f},{0.f,0.f,0.f,0.f},{0.f,0.f,0.f,0.f}};
    f32x4 OaccB[4] = {{0.f,0.f,0.f,0.f},{0.f,0.f,0.f,0.f},{0.f,0.f,0.f,0.f},{0.f,0.f,0.f,0.f}};
    f32x4 Oacc4A = {0.f, 0.f, 0.f, 0.f};
    f32x4 Oacc4B = {0.f, 0.f, 0.f, 0.f};
    float m_runA = NEGINF, m_runB = NEGINF;
    float mmA = NEGINF * LOG2E, mmB = NEGINF * LOG2E;
    float negv = NEGINF;

    // staging mapping: 512 threads, thread stages 8 K elems + 8 V elems
    const int sr  = tid >> 3;          // 0..63
    const int sc8 = (tid & 7) * 8;     // 0..56
    const int srp = (sr & 0x23) | ((sr & 0x18) >> 1) | ((sr & 0x4) << 2);

    const int kw = srp * 128 + ((sc8 * 2) ^ ((srp & 7) << 4));
    const int vw = sr  * 128 + ((sc8 * 2) ^ ((sr  & 7) << 4));
    const int rb0 = ll * 128 + (((lg * 16))      ^ ((ll & 7) << 4));
    const int rb1 = ll * 128 + (((64 + lg * 16)) ^ ((ll & 7) << 4));

    char* const KB = (char*)Kl;
    char* const VB = (char*)Vt;

    const _Float16* gK = hb  + (long)(kv_base + sr) * 64 + sc8;
    const _Float16* gV = hTb + (long)sr * kN + kv_base + sc8;

    // wave-uniform lane-mask pointers (one per q16 group)
    const int wuni = __builtin_amdgcn_readfirstlane(wave);
    const uint64_t* __restrict__ wmpA =
        wmask + ((long)(blockIdx.x * 16 + wuni * 2) * 64 + (kv_base >> 6)) * 16;
    const uint64_t* __restrict__ wmpB = wmpA + (long)64 * 16;

    // ---- stage tile 0 ----
    {
        const f16x8 a0 = *(const f16x8*)(gK);
        const f16x8 b0 = *(const f16x8*)(gV);
        *(f16x8*)(KB + kw) = a0;
        *(f16x8*)(VB + vw) = b0;
        gK += 64 * 64;  gV += 64;
    }

    union PF { half2_t hh[4]; f16x8 v; };

#define SOFTMAX_FRAG(S_, WM_, OACC_, OACC4_, MRUN_, MM_, PF1_, PF2_)             \
    do {                                                                         \
        _Pragma("unroll")                                                        \
        for (int t = 0; t < 4; ++t) {                                            \
            _Pragma("unroll")                                                    \
            for (int rr = 0; rr < 4; ++rr) {                                     \
                float sv = S_[t][rr];                                            \
                asm("v_cndmask_b32 %0, %1, %2, %3"                               \
                    : "=v"(sv) : "v"(negv), "v"(sv), "s"(WM_[t * 4 + rr]));      \
                S_[t][rr] = sv;                                                  \
            }                                                                    \
        }                                                                        \
        float mx0 = fmaxf(fmaxf(S_[0][0], S_[0][1]), fmaxf(S_[0][2], S_[0][3])); \
        float mx1 = fmaxf(fmaxf(S_[1][0], S_[1][1]), fmaxf(S_[1][2], S_[1][3])); \
        float mx2 = fmaxf(fmaxf(S_[2][0], S_[2][1]), fmaxf(S_[2][2], S_[2][3])); \
        float mx3 = fmaxf(fmaxf(S_[3][0], S_[3][1]), fmaxf(S_[3][2], S_[3][3])); \
        float mloc = fmaxf(fmaxf(mx0, mx1), fmaxf(mx2, mx3));                    \
        mloc = fmaxf(mloc, __shfl_xor(mloc, 16));                                \
        mloc = fmaxf(mloc, __shfl_xor(mloc, 32));                                \
        if (__any(mloc > MRUN_ + 8.f)) {                                         \
            const float mnew = fmaxf(MRUN_, mloc);                               \
            const float scl  = __builtin_amdgcn_exp2f((MRUN_ - mnew) * LOG2E);   \
            MRUN_ = mnew;                                                        \
            MM_   = mnew * LOG2E;                                                \
            _Pragma("unroll")                                                    \
            for (int dt = 0; dt < 4; ++dt) OACC_[dt] *= scl;                     \
            OACC4_ *= scl;                                                       \
        }                                                                        \
        _Pragma("unroll")                                                        \
        for (int t = 0; t < 4; ++t) {                                            \
            _Pragma("unroll")                                                    \
            for (int rr = 0; rr < 4; ++rr)                                       \
                S_[t][rr] = __builtin_amdgcn_exp2f(fmaf(S_[t][rr], LOG2E, -MM_));\
        }                                                                        \
        PF1_.hh[0] = __builtin_amdgcn_cvt_pkrtz(S_[0][0], S_[0][1]);             \
        PF1_.hh[1] = __builtin_amdgcn_cvt_pkrtz(S_[0][2], S_[0][3]);             \
        PF1_.hh[2] = __builtin_amdgcn_cvt_pkrtz(S_[1][0], S_[1][1]);             \
        PF1_.hh[3] = __builtin_amdgcn_cvt_pkrtz(S_[1][2], S_[1][3]);             \
        PF2_.hh[0] = __builtin_amdgcn_cvt_pkrtz(S_[2][0], S_[2][1]);             \
        PF2_.hh[1] = __builtin_amdgcn_cvt_pkrtz(S_[2][2], S_[2][3]);             \
        PF2_.hh[2] = __builtin_amdgcn_cvt_pkrtz(S_[3][0], S_[3][1]);             \
        PF2_.hh[3] = __builtin_amdgcn_cvt_pkrtz(S_[3][2], S_[3][3]);             \
    } while (0)

#define TILE_BODY(IT, CB, NB)                                                    \
    do {                                                                         \
        const int it_ = (IT);                                                    \
        /* issue next tile's global loads (vmcnt) BEFORE the barrier */          \
        f16x8 nk0{}, nv0{};                                                      \
        if (it_ + 1 < NT) {                                                      \
            nk0 = *(const f16x8*)(gK);                                           \
            nv0 = *(const f16x8*)(gV);                                           \
            gK += 64 * 64;  gV += 64;                                            \
        }                                                                        \
        /* raw barrier: drain LDS only; vmcnt stays in flight */                 \
        asm volatile("s_waitcnt lgkmcnt(0)" ::: "memory");                       \
        __builtin_amdgcn_s_barrier();                                            \
        __builtin_amdgcn_sched_barrier(0);                                       \
        /* current tile's lane-masks (s_load; QK below covers latency) */        \
        uint64_t WMA[16], WMB[16];                                               \
        _Pragma("unroll")                                                        \
        for (int s5 = 0; s5 < 16; ++s5) WMA[s5] = wmpA[(long)it_ * 16 + s5];     \
        _Pragma("unroll")                                                        \
        for (int s5 = 0; s5 < 16; ++s5) WMB[s5] = wmpB[(long)it_ * 16 + s5];     \
        /* QK: each k-read feeds BOTH fragments */                               \
        f32x4 SA[4], SB[4];                                                      \
        __builtin_amdgcn_s_setprio(1);                                           \
        _Pragma("unroll")                                                        \
        for (int t = 0; t < 4; ++t) {                                            \
            const f16x8 k0 = *(const f16x8*)(KB + (CB) + rb0 + t * 2048);        \
            const f16x8 k1 = *(const f16x8*)(KB + (CB) + rb1 + t * 2048);        \
            f32x4 sa = {0.f, 0.f, 0.f, 0.f};                                     \
            f32x4 sb = {0.f, 0.f, 0.f, 0.f};                                     \
            sa = __builtin_amdgcn_mfma_f32_16x16x32_f16(k0, qfA0, sa, 0, 0, 0);  \
            sa = __builtin_amdgcn_mfma_f32_16x16x32_f16(k1, qfA1, sa, 0, 0, 0);  \
            sb = __builtin_amdgcn_mfma_f32_16x16x32_f16(k0, qfB0, sb, 0, 0, 0);  \
            sb = __builtin_amdgcn_mfma_f32_16x16x32_f16(k1, qfB1, sb, 0, 0, 0);  \
            SA[t] = sa;                                                          \
            SB[t] = sb;                                                          \
        }                                                                        \
        __builtin_amdgcn_s_setprio(0);                                           \
        /* write prefetched tile to the other buffer */                          \
        if (it_ + 1 < NT) {                                                      \
            *(f16x8*)(KB + (NB) + kw) = nk0;                                     \
            *(f16x8*)(VB + (NB) + vw) = nv0;                                     \
        }                                                                        \
        PF pfA1, pfA2, pfB1, pfB2;                                               \
        SOFTMAX_FRAG(SA, WMA, OaccA, Oacc4A, m_runA, mmA, pfA1, pfA2);           \
        SOFTMAX_FRAG(SB, WMB, OaccB, Oacc4B, m_runB, mmB, pfB1, pfB2);           \
        /* PV: each v-read feeds BOTH fragments */                               \
        __builtin_amdgcn_s_setprio(1);                                           \
        _Pragma("unroll")                                                        \
        for (int dt = 0; dt < 4; ++dt) {                                         \
            const f16x8 v0 = *(const f16x8*)(VB + (CB) + rb0 + dt * 2048);       \
            const f16x8 v1 = *(const f16x8*)(VB + (CB) + rb1 + dt * 2048);       \
            OaccA[dt] = __builtin_amdgcn_mfma_f32_16x16x32_f16(v0, pfA1.v, OaccA[dt], 0, 0, 0); \
            OaccA[dt] = __builtin_amdgcn_mfma_f32_16x16x32_f16(v1, pfA2.v, OaccA[dt], 0, 0, 0); \
            OaccB[dt] = __builtin_amdgcn_mfma_f32_16x16x32_f16(v0, pfB1.v, OaccB[dt], 0, 0, 0); \
            OaccB[dt] = __builtin_amdgcn_mfma_f32_16x16x32_f16(v1, pfB2.v, OaccB[dt], 0, 0, 0); \
        }                                                                        \
        Oacc4A = __builtin_amdgcn_mfma_f32_16x16x32_f16(vone, pfA1.v, Oacc4A, 0, 0, 0); \
        Oacc4A = __builtin_amdgcn_mfma_f32_16x16x32_f16(vone, pfA2.v, Oacc4A, 0, 0, 0); \
        Oacc4B = __builtin_amdgcn_mfma_f32_16x16x32_f16(vone, pfB1.v, Oacc4B, 0, 0, 0); \
        Oacc4B = __builtin_amdgcn_mfma_f32_16x16x32_f16(vone, pfB2.v, Oacc4B, 0, 0, 0); \
        __builtin_amdgcn_s_setprio(0);                                           \
    } while (0)

    for (int ith = 0; ith < NT; ith += 2) {
        TILE_BODY(ith,     0,    8192);
        TILE_BODY(ith + 1, 8192, 0);
    }
#undef TILE_BODY
#undef SOFTMAX_FRAG

    // ---- l broadcast ----
    const float lsumA = __shfl(Oacc4A[0], ll, 64);
    const float lsumB = __shfl(Oacc4B[0], ll, 64);
    const float invA  = (lsumA > 0.f) ? (1.0f / lsumA) : 0.f;
    const float invB  = (lsumB > 0.f) ? (1.0f / lsumB) : 0.f;

    // ---- epilogue: lane owns q = {qA, qB}, d = 16*dt + 4*lg + rr ----
    if (outp != nullptr) {
        #pragma unroll
        for (int dt = 0; dt < 4; ++dt) {
            const int dbase = dt * 16 + lg * 4;
            const f32x4 bv = *(const f32x4*)(bias + dbase);
            f32x4 oa, ob;
            #pragma unroll
            for (int rr = 0; rr < 4; ++rr) {
                oa[rr] = OaccA[dt][rr] * invA + bv[rr];
                ob[rr] = OaccB[dt][rr] * invB + bv[rr];
            }
            *(f32x4*)(outp + ((long)b * kN + qA) * 64 + dbase) = oa;
            *(f32x4*)(outp + ((long)b * kN + qB) * 64 + dbase) = ob;
        }
    } else {
        const long srowA = (long)split * kB * kN + (long)b * kN + qA;
        const long srowB = srowA + 16;
        #pragma unroll
        for (int dt = 0; dt < 4; ++dt) {
            const int dbase = dt * 16 + lg * 4;
            f16x4 pa, pb;
            #pragma unroll
            for (int rr = 0; rr < 4; ++rr) {
                pa[rr] = (_Float16)(OaccA[dt][rr] * invA);
                pb[rr] = (_Float16)(OaccB[dt][rr] * invB);
            }
            *(f16x4*)(pO + srowA * 64 + dbase) = pa;
            *(f16x4*)(pO + srowB * 64 + dbase) = pb;
        }
        if (lane < 16) {
            pml[srowA * 2 + 0] = m_runA;
            pml[srowA * 2 + 1] = lsumA;
            pml[srowB * 2 + 0] = m_runB;
            pml[srowB * 2 + 1] = lsumB;
        }
    }
}

// ---------------------------------------------------------------------------
// Kernel 4: combine split-KV partials (normalized f16; weight = l*e^(m-M)).
// ---------------------------------------------------------------------------
__global__ __launch_bounds__(256) void combine_kernel(const _Float16* __restrict__ pO,
                                                      const float* __restrict__ pml,
                                                      const float* __restrict__ bias,
                                                      float* __restrict__ outp,
                                                      int ks)
{
    const long idx = (long)blockIdx.x * 256 + threadIdx.x;  // B*N*16 groups
    const long row = idx >> 4;
    const int  d4  = (int)(idx & 15) * 4;

    float M = NEGINF;
    for (int s = 0; s < ks; ++s)
        M = fmaxf(M, pml[((long)s * kB * kN + row) * 2]);

    float L = 0.f;
    f32x4 acc = {0.f, 0.f, 0.f, 0.f};
    for (int s = 0; s < ks; ++s) {
        const long srow = (long)s * kB * kN + row;
        const float m = pml[srow * 2 + 0];
        const float l = pml[srow * 2 + 1];
        const float w = l * __builtin_amdgcn_exp2f((m - M) * LOG2E);
        L += w;
        const f16x4 o = *(const f16x4*)(pO + srow * 64 + d4);
        #pragma unroll
        for (int j = 0; j < 4; ++j) acc[j] += (float)o[j] * w;
    }
    const float invL = (L > 0.f) ? (1.0f / L) : 0.f;
    const f32x4 bv = *(const f32x4*)(bias + d4);
    *(f32x4*)(outp + row * 64 + d4) = acc * invL + bv;
}

// ---------------------------------------------------------------------------
extern "C" void kernel_launch(void* const* d_in, const int* in_sizes, int n_in,
                              void* d_out, int out_size, void* d_ws, size_t ws_size,
                              hipStream_t stream) {
    const float*  x     = (const float*)d_in[0];   // [8,4096,64]
    const int*    graph = (const int*)d_in[1];     // [4096,4096]
    const float*  W     = (const float*)d_in[2];   // [64,64]
    const float*  bias  = (const float*)d_in[3];   // [64]
    float*        outp  = (float*)d_out;

    char* ws = (char*)d_ws;
    _Float16* hptr  = (_Float16*)ws;                          // 4 MiB @ 0
    uint32_t* mwptr = (uint32_t*)(ws + (4u << 20));           // 2 MiB @ 4M
    _Float16* hTptr = (_Float16*)(ws + (6u << 20));           // 4 MiB @ 6M
    uint64_t* wmptr = (uint64_t*)(ws + (10u << 20));          // 2 MiB @ 10M

    // pO: ks * 4 MiB (f16 normalized), pml: ks * 256 KiB
    int ks = 1;
    if      (ws_size >= ((size_t)30 << 20)) ks = 4;
    else if (ws_size >= ((size_t)21 << 20)) ks = 2;

    _Float16* pO  = (_Float16*)(ws + (12u << 20));
    float*    pml = (float*)(ws + (12u << 20) + (size_t)ks * (4u << 20));

    hproj_kernel<<<dim3(kB * kN / 64), dim3(256), 0, stream>>>(x, W, hptr, hTptr);
    bitpack_kernel<<<dim3(kN * (kN / 32) / 256), dim3(256), 0, stream>>>(graph, mwptr);
    masktr_kernel<<<dim3(256 * 64 / 4), dim3(256), 0, stream>>>(mwptr, wmptr);

    if (ks == 1) {
        attn_kernel<<<dim3(kN / 256, kB, 1), dim3(512), 0, stream>>>(
            hptr, hTptr, wmptr, bias, outp, nullptr, nullptr, kN);
    } else {
        attn_kernel<<<dim3(kN / 256, kB, ks), dim3(512), 0, stream>>>(
            hptr, hTptr, wmptr, bias, nullptr, pO, pml, kN / ks);
        combine_kernel<<<dim3(kB * kN * 16 / 256), dim3(256), 0, stream>>>(
            pO, pml, bias, outp, ks);
    }
}